// Round 16
// baseline (764.298 us; speedup 1.0000x reference)
//
#include <hip/hip_runtime.h>

#define T_DIM 2048
#define B_DIM 32
#define D_DIM 128
#define H_DIM 512
#define L_DIM 6
#define C_DIM 10
#define BN_EPS 1e-5f

constexpr int TB = T_DIM * B_DIM;           // 65536 rows (t-major, then b)
constexpr size_t TBH = (size_t)TB * H_DIM;  // 33,554,432 elements
constexpr size_t PKN = TBH / 2;             // packed u32 count (64 MB)

typedef short s16x8 __attribute__((ext_vector_type(8)));
typedef float f32x16 __attribute__((ext_vector_type(16)));

// ---- bf16 helpers (bit-level, RNE) ----
__device__ inline unsigned short f2bf(float f) {
  unsigned u = __float_as_uint(f);
  unsigned r = (u + 0x7FFFu + ((u >> 16) & 1u)) >> 16;
  return (unsigned short)r;
}
__device__ inline float bf2f(unsigned short b) {
  return __uint_as_float((unsigned)b << 16);
}

// De-interleave 8 packed u32 (evenT | oddT<<16) into two planar s16x8 in LDS.
__device__ inline void destage(uint4 q0, uint4 q1, unsigned short* dlo,
                               unsigned short* dhi) {
  uint4 lo, hi;
  lo.x = __builtin_amdgcn_perm(q0.y, q0.x, 0x05040100u);
  lo.y = __builtin_amdgcn_perm(q0.w, q0.z, 0x05040100u);
  lo.z = __builtin_amdgcn_perm(q1.y, q1.x, 0x05040100u);
  lo.w = __builtin_amdgcn_perm(q1.w, q1.z, 0x05040100u);
  hi.x = __builtin_amdgcn_perm(q0.y, q0.x, 0x07060302u);
  hi.y = __builtin_amdgcn_perm(q0.w, q0.z, 0x07060302u);
  hi.z = __builtin_amdgcn_perm(q1.y, q1.x, 0x07060302u);
  hi.w = __builtin_amdgcn_perm(q1.w, q1.z, 0x07060302u);
  *(uint4*)dlo = lo;
  *(uint4*)dhi = hi;
}

// ---------------------------------------------------------------------------
// bf16 MFMA GEMM over t-pair-packed activations, fully in-place:
//   z[t,b,o] = sum_k s[t,b,k] * W[o,k] + bias[o],  N = 512 fixed.
// Block i covers t-pair i (64 rows = 32 b x 2 t); packed u32 (t,b,h) lives
// at i*16384 + b*512 + h -> block reads AND writes exactly its own region.
// 512 threads (8 waves), wave = 64 rows x 64 cols; acc[0]=t-even, acc[1]=
// t-odd (same b). A staged PLANAR bf16 in K-chunks of BKC (double-buffered
// LDS; store-side destage for packed input). W (split hi/lo bf16) read from
// global in pre-swizzled fragment order with ring-2 register prefetch.
// 2-term MFMA: A*Wh + A*Wl.
// R16: COALESCED EPILOGUE -- the old epilogue issued 32 scattered u32
// stores/thread (two 128-B segments per wave-instr, 2 KB apart); R15's
// layer-0 (1/4 the MFMA work) matching K=512's duration showed block
// lifetime is NOT in the K-loop -> store path suspected. Now C funnels
// through the freed A-LDS (reinterpreted) in NP passes: bank-clean
// ds_writes, then fully-coalesced 16B/lane uint4 global stores.
// W fragment layout: elem (o,k) at ((c32*NIT+itg)*64 + kg*32 + r31)*8 + j.
// Also zeroes stats[0..1023] from block 0 (bn_fold precedes in stream order).
// ---------------------------------------------------------------------------
#define ROWS 64

template <int K, int BKC, bool PACKED_IN>
__global__ __launch_bounds__(512, 4) void gemm_mfma(
    const void* src, const unsigned short* __restrict__ Whi,
    const unsigned short* __restrict__ Wlo, const float* __restrict__ bias,
    uint* __restrict__ dstP, float* stats) {
  constexpr int NC = K / BKC;      // 2 (layer 0) or 4 (K=512)
  constexpr int NITC = BKC / 16;   // MFMA k-steps per chunk
  constexpr int NIT = K / 16;
  constexpr int GM = BKC / 8 - 1;  // granule swizzle mask
  __shared__ __align__(16) unsigned short AhS[2][ROWS * BKC];

  const int tid = threadIdx.x;
  if (blockIdx.x == 0) {  // fold zero_stats into the GEMM
    stats[tid] = 0.f;
    stats[tid + 512] = 0.f;
  }
  const int lane = tid & 63;
  const int wave = tid >> 6;  // 0..7 = col-group of 64
  const int r31 = lane & 31;
  const int kg = lane >> 5;

  const size_t pbase = (size_t)blockIdx.x * 16384;  // block's u32 region
  const uint* srcP = (const uint*)src;
  const float* srcF = (const float*)src;
  const size_t row0 = (size_t)blockIdx.x * ROWS;  // f32-path row base

  // W fragment bases for this wave's two col-frags (coalesced 16B/lane)
  const unsigned short* pWh0 =
      Whi + ((size_t)(wave * 2 + 0) * NIT * 64 + lane) * 8;
  const unsigned short* pWh1 =
      Whi + ((size_t)(wave * 2 + 1) * NIT * 64 + lane) * 8;
  const unsigned short* pWl0 =
      Wlo + ((size_t)(wave * 2 + 0) * NIT * 64 + lane) * 8;
  const unsigned short* pWl1 =
      Wlo + ((size_t)(wave * 2 + 1) * NIT * 64 + lane) * 8;

  // staging geometry
  const int sr0 = tid >> 4, sk0 = tid & 15;
  const int ss0 = sr0 * BKC + ((sk0 ^ (sr0 & GM)) << 3);
  const int ss1 = (sr0 + 32) * BKC + ((sk0 ^ ((sr0 + 32) & GM)) << 3);
  const int srf = tid >> 3, skf = tid & 7;
  const int ssf = srf * BKC + ((skf ^ (srf & GM)) << 3);

  auto cvt8 = [&](float4 a, float4 b) {
    float vv[8] = {a.x, a.y, a.z, a.w, b.x, b.y, b.z, b.w};
    s16x8 hi;
#pragma unroll
    for (int j = 0; j < 8; ++j) hi[j] = (short)f2bf(vv[j]);
    return hi;
  };

  // ---- prologue: stage chunk 0 ----
  if (PACKED_IN) {
    uint4 q0 = *(const uint4*)(srcP + pbase + sr0 * 512 + sk0 * 8);
    uint4 q1 = *(const uint4*)(srcP + pbase + sr0 * 512 + sk0 * 8 + 4);
    destage(q0, q1, &AhS[0][ss0], &AhS[0][ss1]);
  } else {
    const size_t g = (row0 + srf) * K + skf * 8;
    *(s16x8*)&AhS[0][ssf] =
        cvt8(*(const float4*)(srcF + g), *(const float4*)(srcF + g + 4));
  }
  // ---- W ring prologue: fragment itg=0 into slot 0 ----
  s16x8 whr[2][2], wlr[2][2];
  whr[0][0] = *(const s16x8*)pWh0;
  whr[0][1] = *(const s16x8*)pWh1;
  wlr[0][0] = *(const s16x8*)pWl0;
  wlr[0][1] = *(const s16x8*)pWl1;
  __syncthreads();

  f32x16 acc[2][2] = {};
  uint4 q0, q1;   // in-flight next-chunk A (packed)
  float4 f0, f1;  // in-flight next-chunk A (f32)
#pragma unroll
  for (int c = 0; c < NC; ++c) {
    if (c + 1 < NC) {  // issue next chunk's loads (hide under MFMAs)
      if (PACKED_IN) {
        q0 = *(const uint4*)(srcP + pbase + sr0 * 512 + (c + 1) * BKC +
                             sk0 * 8);
        q1 = *(const uint4*)(srcP + pbase + sr0 * 512 + (c + 1) * BKC +
                             sk0 * 8 + 4);
      } else {
        const size_t g = (row0 + srf) * K + (c + 1) * BKC + skf * 8;
        f0 = *(const float4*)(srcF + g);
        f1 = *(const float4*)(srcF + g + 4);
      }
    }
    const int bsel = c & 1;
#pragma unroll
    for (int it = 0; it < NITC; ++it) {
      const int itg = c * NITC + it;
      const int sl = it & 1, sn = (it + 1) & 1;
      if (itg + 1 < NIT) {  // ring-2 W prefetch
        whr[sn][0] = *(const s16x8*)(pWh0 + (size_t)(itg + 1) * 512);
        whr[sn][1] = *(const s16x8*)(pWh1 + (size_t)(itg + 1) * 512);
        wlr[sn][0] = *(const s16x8*)(pWl0 + (size_t)(itg + 1) * 512);
        wlr[sn][1] = *(const s16x8*)(pWl1 + (size_t)(itg + 1) * 512);
      }
      const int gi = it * 2 + kg;
      s16x8 ah[2];
#pragma unroll
      for (int rf = 0; rf < 2; ++rf) {
        const int row = rf * 32 + r31;
        ah[rf] =
            *(const s16x8*)&AhS[bsel][row * BKC + ((gi ^ (row & GM)) << 3)];
      }
      // term-major: 4 independent MFMAs between touches of the same acc
#pragma unroll
      for (int cf = 0; cf < 2; ++cf)
#pragma unroll
        for (int rf = 0; rf < 2; ++rf)
          acc[rf][cf] = __builtin_amdgcn_mfma_f32_32x32x16_bf16(
              ah[rf], whr[sl][cf], acc[rf][cf], 0, 0, 0);
#pragma unroll
      for (int cf = 0; cf < 2; ++cf)
#pragma unroll
        for (int rf = 0; rf < 2; ++rf)
          acc[rf][cf] = __builtin_amdgcn_mfma_f32_32x32x16_bf16(
              ah[rf], wlr[sl][cf], acc[rf][cf], 0, 0, 0);
    }
    if (c + 1 < NC) {  // stage next chunk into the other LDS buffer
      const int nb = (c + 1) & 1;
      if (PACKED_IN) {
        destage(q0, q1, &AhS[nb][ss0], &AhS[nb][ss1]);
      } else {
        *(s16x8*)&AhS[nb][ssf] = cvt8(f0, f1);
      }
      __syncthreads();
    }
  }

  // ---- epilogue (coalesced via LDS funnel) ----
  // acc[0]=t-even, acc[1]=t-odd (same b). mb = (r&3)+8*(r>>2)+4*kg = b.
  // Pass p covers mb in [p*RP, (p+1)*RP): r in [p*RP/2, p*RP/2 + RP/2).
  {
    uint* Cs = (uint*)&AhS[0][0];
    constexpr int CAP = ROWS * BKC;      // LDS capacity in u32
    constexpr int RP = CAP / 512;        // rows per pass (16 or 8)
    constexpr int NP = 32 / RP;          // passes (2 or 4)
    constexpr int NQ = CAP / 2048;       // uint4 copies per thread per pass
    const int o0 = wave * 64 + r31;
    const float bb0 = bias[o0];
    const float bb1 = bias[o0 + 32];
    __syncthreads();  // all A ds_reads done before LDS reuse
#pragma unroll
    for (int p = 0; p < NP; ++p) {
#pragma unroll
      for (int j = 0; j < RP / 2; ++j) {
        const int r = p * (RP / 2) + j;
        const int mb = (r & 3) + 8 * (r >> 2) + 4 * kg;
        const int lr = mb - p * RP;
        const float e0 = acc[0][0][r] + bb0;
        const float d0 = acc[1][0][r] + bb0;
        const float e1 = acc[0][1][r] + bb1;
        const float d1 = acc[1][1][r] + bb1;
        Cs[lr * 512 + o0] = (uint)f2bf(e0) | ((uint)f2bf(d0) << 16);
        Cs[lr * 512 + o0 + 32] = (uint)f2bf(e1) | ((uint)f2bf(d1) << 16);
      }
      __syncthreads();  // funnel writes visible
#pragma unroll
      for (int qd = 0; qd < NQ; ++qd) {
        uint4 v = *(const uint4*)&Cs[qd * 2048 + tid * 4];
        *(uint4*)&dstP[pbase + (size_t)p * CAP + qd * 2048 + tid * 4] = v;
      }
      if (p + 1 < NP) __syncthreads();  // copy reads done before overwrite
    }
  }
}

// ---------------------------------------------------------------------------
// IndRNN scan over packed z (u32 = bf16 z[2i] | bf16 z[2i+1]<<16), in-place:
// overwrites each u32 with packed bf16 s (bit-RNE). State in f32; stats
// accumulated on the ROUNDED s (what the next GEMM consumes).
// One thread per (b,h); CH=32 u32 chunks, register double-buffered.
// ---------------------------------------------------------------------------
__global__ __launch_bounds__(64) void indrnn_scan(uint* __restrict__ z,
                                                  const float* __restrict__ u,
                                                  float* __restrict__ stats) {
  const int gid = blockIdx.x * 64 + threadIdx.x;  // 0..16383
  const int h = gid & (H_DIM - 1);
  const float uu = u[h];
  float hh = 0.f, sum = 0.f, sumsq = 0.f;
  uint* p = z + gid;
  constexpr int STRIDE = B_DIM * H_DIM;  // 16384 u32
  constexpr int NI = T_DIM / 2;          // 1024 packed items per chain
  constexpr int CH = 32;
  constexpr int NCH = NI / CH;  // 32 chunks
  uint va[CH], vb[CH];

#define LOADC(dst, base)                                        \
  _Pragma("unroll") for (int c = 0; c < CH; ++c) dst[c] =       \
      p[(size_t)((base) + c) * STRIDE];
#define COMPC(dst)                                              \
  _Pragma("unroll") for (int c = 0; c < CH; ++c) {              \
    uint pk = dst[c];                                           \
    float ze = __uint_as_float(pk << 16);                       \
    float zo = __uint_as_float(pk & 0xffff0000u);               \
    hh = fmaxf(ze + uu * hh, 0.f);                              \
    unsigned short he = f2bf(hh);                               \
    float se = bf2f(he);                                        \
    sum += se; sumsq += se * se;                                \
    hh = fmaxf(zo + uu * hh, 0.f);                              \
    unsigned short ho = f2bf(hh);                               \
    float so = bf2f(ho);                                        \
    sum += so; sumsq += so * so;                                \
    dst[c] = (uint)he | ((uint)ho << 16);                       \
  }
#define STOREC(dst, base)                                       \
  _Pragma("unroll") for (int c = 0; c < CH; ++c)                \
      p[(size_t)((base) + c) * STRIDE] = dst[c];

  LOADC(va, 0)
  for (int i = 0; i < (NCH - 2) / 2; ++i) {
    const int t0 = i * 2 * CH;
    LOADC(vb, t0 + CH)
    COMPC(va)
    STOREC(va, t0)
    LOADC(va, t0 + 2 * CH)
    COMPC(vb)
    STOREC(vb, t0 + CH)
  }
  {
    const int t0 = (NCH - 2) * CH;
    LOADC(vb, t0 + CH)
    COMPC(va)
    STOREC(va, t0)
    COMPC(vb)
    STOREC(vb, t0 + CH)
  }
#undef LOADC
#undef COMPC
#undef STOREC
  atomicAdd(&stats[h], sum);
  atomicAdd(&stats[H_DIM + h], sumsq);
}

__global__ __launch_bounds__(64) void fill_sentinel(float* __restrict__ out,
                                                    int n) {
  for (int i = threadIdx.x; i < n; i += 64) out[i] = 1.0e6f;
}

// ---------------------------------------------------------------------------
// Convert raw f32 weights (layer 0) to bf16 hi/lo in fragment-swizzled order.
// ---------------------------------------------------------------------------
template <int K>
__global__ __launch_bounds__(256) void convert_w(
    const float* __restrict__ W, unsigned short* __restrict__ Whi,
    unsigned short* __restrict__ Wlo) {
  constexpr int NIT = K / 16;
  int i = blockIdx.x * 256 + threadIdx.x;
  if (i < H_DIM * K) {
    int o = i / K, k = i % K;
    float v = W[i];
    unsigned short h = f2bf(v);
    size_t idx =
        ((size_t)((o >> 5) * NIT + (k >> 4)) * 64 + ((k >> 3) & 1) * 32 +
         (o & 31)) * 8 + (k & 7);
    Whi[idx] = h;
    Wlo[idx] = f2bf(v - bf2f(h));
  }
}

// ---------------------------------------------------------------------------
// Fold BN of previous layer into next layer's weights, emit swizzled bf16:
//   a[i] = gamma[i]*rsqrt(var[i]+eps); c[i] = beta[i] - mean[i]*a[i]
//   Wf[o,i] = Wn[o,i]*a[i];  bf[o] = bn[o] + sum_i Wn[o,i]*c[i]
// ---------------------------------------------------------------------------
__global__ __launch_bounds__(256) void bn_fold(
    const float* __restrict__ stats, const float* __restrict__ gamma,
    const float* __restrict__ beta, const float* __restrict__ Wn,
    const float* __restrict__ bn, unsigned short* __restrict__ Whi,
    unsigned short* __restrict__ Wlo, float* __restrict__ bf) {
  constexpr int NIT = H_DIM / 16;
  const int o = blockIdx.x;
  const int tid = threadIdx.x;
  constexpr float invTB = 1.f / (float)(T_DIM * B_DIM);
  float part = 0.f;
  for (int i = tid; i < H_DIM; i += 256) {
    float mean = stats[i] * invTB;
    float var = stats[H_DIM + i] * invTB - mean * mean;
    float a = gamma[i] * rsqrtf(var + BN_EPS);
    float c = beta[i] - mean * a;
    float w = Wn[(size_t)o * H_DIM + i];
    float wf = w * a;
    unsigned short h = f2bf(wf);
    size_t idx =
        ((size_t)((o >> 5) * NIT + (i >> 4)) * 64 + ((i >> 3) & 1) * 32 +
         (o & 31)) * 8 + (i & 7);
    Whi[idx] = h;
    Wlo[idx] = f2bf(wf - bf2f(h));
    part += w * c;
  }
  __shared__ float red[256];
  red[tid] = part;
  __syncthreads();
  for (int s = 128; s > 0; s >>= 1) {
    if (tid < s) red[tid] += red[tid + s];
    __syncthreads();
  }
  if (tid == 0) bf[o] = bn[o] + red[0];
}

// ---------------------------------------------------------------------------
// Final: out[b,c] = sum_i (s5[T-1,b,i]*a5[i] + c5[i]) * Wout[c,i] + bout[c]
// s5 packed: t=2047 is the HIGH half of packed item i=1023.
// ---------------------------------------------------------------------------
__global__ __launch_bounds__(64) void final_out(const uint* __restrict__ s5,
                                                const float* __restrict__ stats,
                                                const float* __restrict__ gamma,
                                                const float* __restrict__ beta,
                                                const float* __restrict__ Wout,
                                                const float* __restrict__ bout,
                                                float* __restrict__ out) {
  const int b = blockIdx.x / C_DIM, cls = blockIdx.x % C_DIM;
  const int lane = threadIdx.x;
  constexpr float invTB = 1.f / (float)(T_DIM * B_DIM);
  const uint* srow =
      s5 + (size_t)(T_DIM / 2 - 1) * B_DIM * H_DIM + (size_t)b * H_DIM;
  float part = 0.f;
  for (int i = lane; i < H_DIM; i += 64) {
    float mean = stats[i] * invTB;
    float var = stats[H_DIM + i] * invTB - mean * mean;
    float a = gamma[i] * rsqrtf(var + BN_EPS);
    float c = beta[i] - mean * a;
    float sval = __uint_as_float(srow[i] & 0xffff0000u);
    part += (sval * a + c) * Wout[(size_t)cls * H_DIM + i];
  }
#pragma unroll
  for (int off = 32; off > 0; off >>= 1) part += __shfl_down(part, off);
  if (lane == 0) out[b * C_DIM + cls] = part + bout[cls];
}

// ---------------------------------------------------------------------------
extern "C" void kernel_launch(void* const* d_in, const int* in_sizes, int n_in,
                              void* d_out, int out_size, void* d_ws,
                              size_t ws_size, hipStream_t stream) {
  const float* x     = (const float*)d_in[0];
  const float* W0    = (const float*)d_in[1];
  const float* b0    = (const float*)d_in[2];
  const float* Wh    = (const float*)d_in[3];
  const float* bh    = (const float*)d_in[4];
  const float* u     = (const float*)d_in[5];
  const float* gamma = (const float*)d_in[6];
  const float* beta  = (const float*)d_in[7];
  const float* Wout  = (const float*)d_in[8];
  const float* bout  = (const float*)d_in[9];
  float* out = (float*)d_out;

  const size_t need = PKN * sizeof(uint) +
                      (size_t)H_DIM * H_DIM * 2 * sizeof(unsigned short) +
                      3 * H_DIM * sizeof(float);
  if (ws_size < need) {
    fill_sentinel<<<1, 64, 0, stream>>>(out, out_size);
    return;
  }

  uint* buf = (uint*)d_ws;                             // 64 MB packed acts
  unsigned short* Whi = (unsigned short*)(buf + PKN);  // 512 KB
  unsigned short* Wlo = Whi + (size_t)H_DIM * H_DIM;   // 512 KB
  float* bf = (float*)(Wlo + (size_t)H_DIM * H_DIM);   // 2 KB
  float* stats = bf + H_DIM;                           // 4 KB

  const int gemm_blocks = TB / ROWS;  // 1024
  const int scan_blocks = (B_DIM * H_DIM) / 64;

  // ---- layer 0: x (f32, K=128, BKC=64 -> NC=2 pipelined) -> buf ----
  convert_w<D_DIM><<<(H_DIM * D_DIM + 255) / 256, 256, 0, stream>>>(W0, Whi,
                                                                    Wlo);
  gemm_mfma<D_DIM, 64, false><<<gemm_blocks, 512, 0, stream>>>(x, Whi, Wlo,
                                                               b0, buf, stats);
  indrnn_scan<<<scan_blocks, 64, 0, stream>>>(buf, u, stats);

  // ---- layers 1..5: fully in-place on the 64 MB packed buffer ----
  for (int l = 1; l < L_DIM; ++l) {
    bn_fold<<<H_DIM, 256, 0, stream>>>(
        stats, gamma + (size_t)(l - 1) * H_DIM, beta + (size_t)(l - 1) * H_DIM,
        Wh + (size_t)(l - 1) * H_DIM * H_DIM, bh + (size_t)(l - 1) * H_DIM,
        Whi, Wlo, bf);
    gemm_mfma<H_DIM, 128, true><<<gemm_blocks, 512, 0, stream>>>(
        buf, Whi, Wlo, bf, buf, stats);
    indrnn_scan<<<scan_blocks, 64, 0, stream>>>(buf, u + (size_t)l * H_DIM,
                                                stats);
  }

  // ---- final projection (BN of layer 5 applied on the fly) ----
  final_out<<<B_DIM * C_DIM, 64, 0, stream>>>(
      buf, stats, gamma + 5 * (size_t)H_DIM, beta + 5 * (size_t)H_DIM, Wout,
      bout, out);
}

// Round 17
// 571.037 us; speedup vs baseline: 1.3384x; 1.3384x over previous
//
#include <hip/hip_runtime.h>

#define T_DIM 2048
#define B_DIM 32
#define D_DIM 128
#define H_DIM 512
#define L_DIM 6
#define C_DIM 10
#define BN_EPS 1e-5f

constexpr int TB = T_DIM * B_DIM;           // 65536 rows (t-major, then b)
constexpr size_t TBH = (size_t)TB * H_DIM;  // 33,554,432 elements
constexpr size_t PKN = TBH / 2;             // packed u32 count (64 MB)

typedef short s16x8 __attribute__((ext_vector_type(8)));
typedef float f32x16 __attribute__((ext_vector_type(16)));

// ---- bf16 helpers (bit-level, RNE) ----
__device__ inline unsigned short f2bf(float f) {
  unsigned u = __float_as_uint(f);
  unsigned r = (u + 0x7FFFu + ((u >> 16) & 1u)) >> 16;
  return (unsigned short)r;
}
__device__ inline float bf2f(unsigned short b) {
  return __uint_as_float((unsigned)b << 16);
}

// De-interleave 8 packed u32 (evenT | oddT<<16) into two planar s16x8 in LDS.
__device__ inline void destage(uint4 q0, uint4 q1, unsigned short* dlo,
                               unsigned short* dhi) {
  uint4 lo, hi;
  lo.x = __builtin_amdgcn_perm(q0.y, q0.x, 0x05040100u);
  lo.y = __builtin_amdgcn_perm(q0.w, q0.z, 0x05040100u);
  lo.z = __builtin_amdgcn_perm(q1.y, q1.x, 0x05040100u);
  lo.w = __builtin_amdgcn_perm(q1.w, q1.z, 0x05040100u);
  hi.x = __builtin_amdgcn_perm(q0.y, q0.x, 0x07060302u);
  hi.y = __builtin_amdgcn_perm(q0.w, q0.z, 0x07060302u);
  hi.z = __builtin_amdgcn_perm(q1.y, q1.x, 0x07060302u);
  hi.w = __builtin_amdgcn_perm(q1.w, q1.z, 0x07060302u);
  *(uint4*)dlo = lo;
  *(uint4*)dhi = hi;
}

// ---------------------------------------------------------------------------
// bf16 MFMA GEMM over t-pair-packed activations, fully in-place:
//   z[t,b,o] = sum_k s[t,b,k] * W[o,k] + bias[o],  N = 512 fixed.
// Block i covers t-pair i (64 rows = 32 b x 2 t); packed u32 (t,b,h) lives
// at i*16384 + b*512 + h -> block reads AND writes exactly its own region.
// 512 threads (8 waves), wave = 64 rows x 64 cols; acc[0]=t-even, acc[1]=
// t-odd (same b). A staged PLANAR bf16 in K-chunks of BKC (double-buffered
// LDS; store-side destage for packed input). W: SINGLE bf16 (1-term MFMA --
// R17: the lo-term dropped; activation-bf16 error already dominates), read
// from global in pre-swizzled fragment order with RING-4 register prefetch
// (R17: ring-2's 1-step lookahead ~100cyc < L2 latency ~200cyc was the
// per-K-step stall -- the 50%-idle signature of R4..R16; 3-step lookahead
// covers it at identical VGPR cost since the lo-ring is gone).
// Coalesced epilogue via LDS funnel (R16, traffic-neutral but kept).
// W fragment layout: elem (o,k) at ((c32*NIT+itg)*64 + kg*32 + r31)*8 + j.
// Also zeroes stats[0..1023] from block 0 (bn_fold precedes in stream order).
// ---------------------------------------------------------------------------
#define ROWS 64

template <int K, int BKC, bool PACKED_IN>
__global__ __launch_bounds__(512, 4) void gemm_mfma(
    const void* src, const unsigned short* __restrict__ Whi,
    const float* __restrict__ bias, uint* __restrict__ dstP, float* stats) {
  constexpr int NC = K / BKC;      // 2 (layer 0) or 4 (K=512)
  constexpr int NITC = BKC / 16;   // MFMA k-steps per chunk
  constexpr int NIT = K / 16;
  constexpr int GM = BKC / 8 - 1;  // granule swizzle mask
  __shared__ __align__(16) unsigned short AhS[2][ROWS * BKC];

  const int tid = threadIdx.x;
  if (blockIdx.x == 0) {  // fold zero_stats into the GEMM
    stats[tid] = 0.f;
    stats[tid + 512] = 0.f;
  }
  const int lane = tid & 63;
  const int wave = tid >> 6;  // 0..7 = col-group of 64
  const int r31 = lane & 31;
  const int kg = lane >> 5;

  const size_t pbase = (size_t)blockIdx.x * 16384;  // block's u32 region
  const uint* srcP = (const uint*)src;
  const float* srcF = (const float*)src;
  const size_t row0 = (size_t)blockIdx.x * ROWS;  // f32-path row base

  // W fragment bases for this wave's two col-frags (coalesced 16B/lane)
  const unsigned short* pWh0 =
      Whi + ((size_t)(wave * 2 + 0) * NIT * 64 + lane) * 8;
  const unsigned short* pWh1 =
      Whi + ((size_t)(wave * 2 + 1) * NIT * 64 + lane) * 8;

  // staging geometry
  const int sr0 = tid >> 4, sk0 = tid & 15;
  const int ss0 = sr0 * BKC + ((sk0 ^ (sr0 & GM)) << 3);
  const int ss1 = (sr0 + 32) * BKC + ((sk0 ^ ((sr0 + 32) & GM)) << 3);
  const int srf = tid >> 3, skf = tid & 7;
  const int ssf = srf * BKC + ((skf ^ (srf & GM)) << 3);

  auto cvt8 = [&](float4 a, float4 b) {
    float vv[8] = {a.x, a.y, a.z, a.w, b.x, b.y, b.z, b.w};
    s16x8 hi;
#pragma unroll
    for (int j = 0; j < 8; ++j) hi[j] = (short)f2bf(vv[j]);
    return hi;
  };

  // ---- prologue: stage chunk 0 ----
  if (PACKED_IN) {
    uint4 q0 = *(const uint4*)(srcP + pbase + sr0 * 512 + sk0 * 8);
    uint4 q1 = *(const uint4*)(srcP + pbase + sr0 * 512 + sk0 * 8 + 4);
    destage(q0, q1, &AhS[0][ss0], &AhS[0][ss1]);
  } else {
    const size_t g = (row0 + srf) * K + skf * 8;
    *(s16x8*)&AhS[0][ssf] =
        cvt8(*(const float4*)(srcF + g), *(const float4*)(srcF + g + 4));
  }
  // ---- W ring prologue: fragments itg=0,1,2 into slots 0,1,2 ----
  s16x8 whr[4][2];
#pragma unroll
  for (int s = 0; s < 3; ++s) {
    whr[s][0] = *(const s16x8*)(pWh0 + (size_t)s * 512);
    whr[s][1] = *(const s16x8*)(pWh1 + (size_t)s * 512);
  }
  __syncthreads();

  f32x16 acc[2][2] = {};
  uint4 q0, q1;   // in-flight next-chunk A (packed)
  float4 f0, f1;  // in-flight next-chunk A (f32)
#pragma unroll
  for (int c = 0; c < NC; ++c) {
    if (c + 1 < NC) {  // issue next chunk's loads (hide under MFMAs)
      if (PACKED_IN) {
        q0 = *(const uint4*)(srcP + pbase + sr0 * 512 + (c + 1) * BKC +
                             sk0 * 8);
        q1 = *(const uint4*)(srcP + pbase + sr0 * 512 + (c + 1) * BKC +
                             sk0 * 8 + 4);
      } else {
        const size_t g = (row0 + srf) * K + (c + 1) * BKC + skf * 8;
        f0 = *(const float4*)(srcF + g);
        f1 = *(const float4*)(srcF + g + 4);
      }
    }
    const int bsel = c & 1;
#pragma unroll
    for (int it = 0; it < NITC; ++it) {
      const int itg = c * NITC + it;
      const int sl = itg & 3;
      if (itg + 3 < NIT) {  // ring-4 W prefetch (3-step lookahead)
        const int sp = (itg + 3) & 3;
        whr[sp][0] = *(const s16x8*)(pWh0 + (size_t)(itg + 3) * 512);
        whr[sp][1] = *(const s16x8*)(pWh1 + (size_t)(itg + 3) * 512);
      }
      const int gi = it * 2 + kg;
      s16x8 ah[2];
#pragma unroll
      for (int rf = 0; rf < 2; ++rf) {
        const int row = rf * 32 + r31;
        ah[rf] =
            *(const s16x8*)&AhS[bsel][row * BKC + ((gi ^ (row & GM)) << 3)];
      }
      // 4 independent MFMAs (1-term: A * Whi)
#pragma unroll
      for (int cf = 0; cf < 2; ++cf)
#pragma unroll
        for (int rf = 0; rf < 2; ++rf)
          acc[rf][cf] = __builtin_amdgcn_mfma_f32_32x32x16_bf16(
              ah[rf], whr[sl][cf], acc[rf][cf], 0, 0, 0);
    }
    if (c + 1 < NC) {  // stage next chunk into the other LDS buffer
      const int nb = (c + 1) & 1;
      if (PACKED_IN) {
        destage(q0, q1, &AhS[nb][ss0], &AhS[nb][ss1]);
      } else {
        *(s16x8*)&AhS[nb][ssf] = cvt8(f0, f1);
      }
      __syncthreads();
    }
  }

  // ---- epilogue (coalesced via LDS funnel) ----
  // acc[0]=t-even, acc[1]=t-odd (same b). mb = (r&3)+8*(r>>2)+4*kg = b.
  {
    uint* Cs = (uint*)&AhS[0][0];
    constexpr int CAP = ROWS * BKC;  // total u32 across both LDS buffers
    constexpr int RP = CAP / 512;    // rows per pass (16 or 8)
    constexpr int NP = 32 / RP;      // passes (2 or 4)
    constexpr int NQ = CAP / 2048;   // uint4 copies per thread per pass
    const int o0 = wave * 64 + r31;
    const float bb0 = bias[o0];
    const float bb1 = bias[o0 + 32];
    __syncthreads();  // all A ds_reads done before LDS reuse
#pragma unroll
    for (int p = 0; p < NP; ++p) {
#pragma unroll
      for (int j = 0; j < RP / 2; ++j) {
        const int r = p * (RP / 2) + j;
        const int mb = (r & 3) + 8 * (r >> 2) + 4 * kg;
        const int lr = mb - p * RP;
        const float e0 = acc[0][0][r] + bb0;
        const float d0 = acc[1][0][r] + bb0;
        const float e1 = acc[0][1][r] + bb1;
        const float d1 = acc[1][1][r] + bb1;
        Cs[lr * 512 + o0] = (uint)f2bf(e0) | ((uint)f2bf(d0) << 16);
        Cs[lr * 512 + o0 + 32] = (uint)f2bf(e1) | ((uint)f2bf(d1) << 16);
      }
      __syncthreads();  // funnel writes visible
#pragma unroll
      for (int qd = 0; qd < NQ; ++qd) {
        uint4 v = *(const uint4*)&Cs[qd * 2048 + tid * 4];
        *(uint4*)&dstP[pbase + (size_t)p * CAP + qd * 2048 + tid * 4] = v;
      }
      if (p + 1 < NP) __syncthreads();  // copy reads done before overwrite
    }
  }
}

// ---------------------------------------------------------------------------
// IndRNN scan over packed z (u32 = bf16 z[2i] | bf16 z[2i+1]<<16), in-place:
// overwrites each u32 with packed bf16 s (bit-RNE). State in f32; stats
// accumulated on the ROUNDED s (what the next GEMM consumes).
// One thread per (b,h); CH=32 u32 chunks, register double-buffered.
// ---------------------------------------------------------------------------
__global__ __launch_bounds__(64) void indrnn_scan(uint* __restrict__ z,
                                                  const float* __restrict__ u,
                                                  float* __restrict__ stats) {
  const int gid = blockIdx.x * 64 + threadIdx.x;  // 0..16383
  const int h = gid & (H_DIM - 1);
  const float uu = u[h];
  float hh = 0.f, sum = 0.f, sumsq = 0.f;
  uint* p = z + gid;
  constexpr int STRIDE = B_DIM * H_DIM;  // 16384 u32
  constexpr int NI = T_DIM / 2;          // 1024 packed items per chain
  constexpr int CH = 32;
  constexpr int NCH = NI / CH;  // 32 chunks
  uint va[CH], vb[CH];

#define LOADC(dst, base)                                        \
  _Pragma("unroll") for (int c = 0; c < CH; ++c) dst[c] =       \
      p[(size_t)((base) + c) * STRIDE];
#define COMPC(dst)                                              \
  _Pragma("unroll") for (int c = 0; c < CH; ++c) {              \
    uint pk = dst[c];                                           \
    float ze = __uint_as_float(pk << 16);                       \
    float zo = __uint_as_float(pk & 0xffff0000u);               \
    hh = fmaxf(ze + uu * hh, 0.f);                              \
    unsigned short he = f2bf(hh);                               \
    float se = bf2f(he);                                        \
    sum += se; sumsq += se * se;                                \
    hh = fmaxf(zo + uu * hh, 0.f);                              \
    unsigned short ho = f2bf(hh);                               \
    float so = bf2f(ho);                                        \
    sum += so; sumsq += so * so;                                \
    dst[c] = (uint)he | ((uint)ho << 16);                       \
  }
#define STOREC(dst, base)                                       \
  _Pragma("unroll") for (int c = 0; c < CH; ++c)                \
      p[(size_t)((base) + c) * STRIDE] = dst[c];

  LOADC(va, 0)
  for (int i = 0; i < (NCH - 2) / 2; ++i) {
    const int t0 = i * 2 * CH;
    LOADC(vb, t0 + CH)
    COMPC(va)
    STOREC(va, t0)
    LOADC(va, t0 + 2 * CH)
    COMPC(vb)
    STOREC(vb, t0 + CH)
  }
  {
    const int t0 = (NCH - 2) * CH;
    LOADC(vb, t0 + CH)
    COMPC(va)
    STOREC(va, t0)
    COMPC(vb)
    STOREC(vb, t0 + CH)
  }
#undef LOADC
#undef COMPC
#undef STOREC
  atomicAdd(&stats[h], sum);
  atomicAdd(&stats[H_DIM + h], sumsq);
}

__global__ __launch_bounds__(64) void fill_sentinel(float* __restrict__ out,
                                                    int n) {
  for (int i = threadIdx.x; i < n; i += 64) out[i] = 1.0e6f;
}

// ---------------------------------------------------------------------------
// Convert raw f32 weights (layer 0) to bf16 in fragment-swizzled order.
// ---------------------------------------------------------------------------
template <int K>
__global__ __launch_bounds__(256) void convert_w(
    const float* __restrict__ W, unsigned short* __restrict__ Whi) {
  constexpr int NIT = K / 16;
  int i = blockIdx.x * 256 + threadIdx.x;
  if (i < H_DIM * K) {
    int o = i / K, k = i % K;
    size_t idx =
        ((size_t)((o >> 5) * NIT + (k >> 4)) * 64 + ((k >> 3) & 1) * 32 +
         (o & 31)) * 8 + (k & 7);
    Whi[idx] = f2bf(W[i]);
  }
}

// ---------------------------------------------------------------------------
// Fold BN of previous layer into next layer's weights, emit swizzled bf16:
//   a[i] = gamma[i]*rsqrt(var[i]+eps); c[i] = beta[i] - mean[i]*a[i]
//   Wf[o,i] = Wn[o,i]*a[i];  bf[o] = bn[o] + sum_i Wn[o,i]*c[i]
// ---------------------------------------------------------------------------
__global__ __launch_bounds__(256) void bn_fold(
    const float* __restrict__ stats, const float* __restrict__ gamma,
    const float* __restrict__ beta, const float* __restrict__ Wn,
    const float* __restrict__ bn, unsigned short* __restrict__ Whi,
    float* __restrict__ bf) {
  constexpr int NIT = H_DIM / 16;
  const int o = blockIdx.x;
  const int tid = threadIdx.x;
  constexpr float invTB = 1.f / (float)(T_DIM * B_DIM);
  float part = 0.f;
  for (int i = tid; i < H_DIM; i += 256) {
    float mean = stats[i] * invTB;
    float var = stats[H_DIM + i] * invTB - mean * mean;
    float a = gamma[i] * rsqrtf(var + BN_EPS);
    float c = beta[i] - mean * a;
    float w = Wn[(size_t)o * H_DIM + i];
    size_t idx =
        ((size_t)((o >> 5) * NIT + (i >> 4)) * 64 + ((i >> 3) & 1) * 32 +
         (o & 31)) * 8 + (i & 7);
    Whi[idx] = f2bf(w * a);
    part += w * c;
  }
  __shared__ float red[256];
  red[tid] = part;
  __syncthreads();
  for (int s = 128; s > 0; s >>= 1) {
    if (tid < s) red[tid] += red[tid + s];
    __syncthreads();
  }
  if (tid == 0) bf[o] = bn[o] + red[0];
}

// ---------------------------------------------------------------------------
// Final: out[b,c] = sum_i (s5[T-1,b,i]*a5[i] + c5[i]) * Wout[c,i] + bout[c]
// s5 packed: t=2047 is the HIGH half of packed item i=1023.
// ---------------------------------------------------------------------------
__global__ __launch_bounds__(64) void final_out(const uint* __restrict__ s5,
                                                const float* __restrict__ stats,
                                                const float* __restrict__ gamma,
                                                const float* __restrict__ beta,
                                                const float* __restrict__ Wout,
                                                const float* __restrict__ bout,
                                                float* __restrict__ out) {
  const int b = blockIdx.x / C_DIM, cls = blockIdx.x % C_DIM;
  const int lane = threadIdx.x;
  constexpr float invTB = 1.f / (float)(T_DIM * B_DIM);
  const uint* srow =
      s5 + (size_t)(T_DIM / 2 - 1) * B_DIM * H_DIM + (size_t)b * H_DIM;
  float part = 0.f;
  for (int i = lane; i < H_DIM; i += 64) {
    float mean = stats[i] * invTB;
    float var = stats[H_DIM + i] * invTB - mean * mean;
    float a = gamma[i] * rsqrtf(var + BN_EPS);
    float c = beta[i] - mean * a;
    float sval = __uint_as_float(srow[i] & 0xffff0000u);
    part += (sval * a + c) * Wout[(size_t)cls * H_DIM + i];
  }
#pragma unroll
  for (int off = 32; off > 0; off >>= 1) part += __shfl_down(part, off);
  if (lane == 0) out[b * C_DIM + cls] = part + bout[cls];
}

// ---------------------------------------------------------------------------
extern "C" void kernel_launch(void* const* d_in, const int* in_sizes, int n_in,
                              void* d_out, int out_size, void* d_ws,
                              size_t ws_size, hipStream_t stream) {
  const float* x     = (const float*)d_in[0];
  const float* W0    = (const float*)d_in[1];
  const float* b0    = (const float*)d_in[2];
  const float* Wh    = (const float*)d_in[3];
  const float* bh    = (const float*)d_in[4];
  const float* u     = (const float*)d_in[5];
  const float* gamma = (const float*)d_in[6];
  const float* beta  = (const float*)d_in[7];
  const float* Wout  = (const float*)d_in[8];
  const float* bout  = (const float*)d_in[9];
  float* out = (float*)d_out;

  const size_t need = PKN * sizeof(uint) +
                      (size_t)H_DIM * H_DIM * sizeof(unsigned short) +
                      3 * H_DIM * sizeof(float);
  if (ws_size < need) {
    fill_sentinel<<<1, 64, 0, stream>>>(out, out_size);
    return;
  }

  uint* buf = (uint*)d_ws;                             // 64 MB packed acts
  unsigned short* Whi = (unsigned short*)(buf + PKN);  // 512 KB
  float* bf = (float*)(Whi + (size_t)H_DIM * H_DIM);   // 2 KB
  float* stats = bf + H_DIM;                           // 4 KB

  const int gemm_blocks = TB / ROWS;  // 1024
  const int scan_blocks = (B_DIM * H_DIM) / 64;

  // ---- layer 0: x (f32, K=128, BKC=64 -> NC=2 pipelined) -> buf ----
  convert_w<D_DIM><<<(H_DIM * D_DIM + 255) / 256, 256, 0, stream>>>(W0, Whi);
  gemm_mfma<D_DIM, 64, false><<<gemm_blocks, 512, 0, stream>>>(x, Whi, b0,
                                                               buf, stats);
  indrnn_scan<<<scan_blocks, 64, 0, stream>>>(buf, u, stats);

  // ---- layers 1..5: fully in-place on the 64 MB packed buffer ----
  for (int l = 1; l < L_DIM; ++l) {
    bn_fold<<<H_DIM, 256, 0, stream>>>(
        stats, gamma + (size_t)(l - 1) * H_DIM, beta + (size_t)(l - 1) * H_DIM,
        Wh + (size_t)(l - 1) * H_DIM * H_DIM, bh + (size_t)(l - 1) * H_DIM,
        Whi, bf);
    gemm_mfma<H_DIM, 128, true><<<gemm_blocks, 512, 0, stream>>>(
        buf, Whi, bf, buf, stats);
    indrnn_scan<<<scan_blocks, 64, 0, stream>>>(buf, u + (size_t)l * H_DIM,
                                                stats);
  }

  // ---- final projection (BN of layer 5 applied on the fly) ----
  final_out<<<B_DIM * C_DIM, 64, 0, stream>>>(
      buf, stats, gamma + 5 * (size_t)H_DIM, beta + 5 * (size_t)H_DIM, Wout,
      bout, out);
}